// Round 1
// baseline (2151.580 us; speedup 1.0000x reference)
//
#include <hip/hip_runtime.h>
#include <hip/hip_bf16.h>
#include <stdint.h>

typedef __attribute__((ext_vector_type(8))) short short8;
typedef __attribute__((ext_vector_type(4))) float f32x4;
typedef unsigned short u16;

#define BATCH 4
#define NH    16
#define SEQ   2048
#define DM    1024
#define HD    64

__device__ __forceinline__ u16 bf16_rne(float f) {
    uint32_t u = __builtin_bit_cast(uint32_t, f);
    uint32_t r = (u + 0x7FFFu + ((u >> 16) & 1u)) >> 16;
    return (u16)r;
}
__device__ __forceinline__ float bf16_to_f(u16 h) {
    uint32_t u = ((uint32_t)h) << 16;
    return __builtin_bit_cast(float, u);
}

// ---------------- K0a: split x into bf16 hi/lo ----------------
__global__ void k_split_x(const float4* __restrict__ x, ushort4* __restrict__ xh,
                          ushort4* __restrict__ xl, int n4) {
    int i = blockIdx.x * 256 + threadIdx.x;
    if (i >= n4) return;
    float4 v = x[i];
    float f[4] = {v.x, v.y, v.z, v.w};
    ushort4 h, l;
    u16* hp = (u16*)&h; u16* lp = (u16*)&l;
#pragma unroll
    for (int j = 0; j < 4; j++) {
        u16 hh = bf16_rne(f[j]);
        hp[j] = hh;
        lp[j] = bf16_rne(f[j] - bf16_to_f(hh));
    }
    xh[i] = h; xl[i] = l;
}

// ---------------- K0b: transpose + split the 4 weight matrices ----------------
// out layout: wt[wi][n][k] (n-major), wi in {q,k,v,o}
__global__ void k_split_w(const float* __restrict__ w0, const float* __restrict__ w1,
                          const float* __restrict__ w2, const float* __restrict__ w3,
                          u16* __restrict__ wth, u16* __restrict__ wtl) {
    __shared__ float tile[32][33];
    int bx = blockIdx.x;
    int wi = bx >> 10;            // 1024 tiles per weight
    int t  = bx & 1023;
    int kt = t >> 5, nt = t & 31;
    const float* w = (wi == 0) ? w0 : (wi == 1) ? w1 : (wi == 2) ? w2 : w3;
    int tx = threadIdx.x & 31, ty = threadIdx.x >> 5;   // ty 0..7
#pragma unroll
    for (int i = 0; i < 4; i++) {
        int r = ty + i * 8;
        tile[r][tx] = w[(size_t)(kt * 32 + r) * 1024 + nt * 32 + tx];
    }
    __syncthreads();
    size_t base = ((size_t)wi << 20);
#pragma unroll
    for (int i = 0; i < 4; i++) {
        int r = ty + i * 8;
        float f = tile[tx][r];    // = w[kt*32+tx][nt*32+r]
        u16 h = bf16_rne(f);
        u16 l = bf16_rne(f - bf16_to_f(h));
        size_t dst = base + (size_t)(nt * 32 + r) * 1024 + kt * 32 + tx;
        wth[dst] = h; wtl[dst] = l;
    }
}

// ---------------- K1: QKV projection GEMM (split-bf16 MFMA) ----------------
// C[8192,3072] = X[8192,1024] @ [Wq|Wk|Wv]; writes q,k (hi/lo, [B,H,S,hd]) and v^T ([B,H,hd,S])
__global__ __launch_bounds__(256) void k_gemm_qkv(
    const u16* __restrict__ xh, const u16* __restrict__ xl,
    const u16* __restrict__ wth, const u16* __restrict__ wtl,
    const float* __restrict__ bq, const float* __restrict__ bk, const float* __restrict__ bv,
    u16* __restrict__ qh, u16* __restrict__ ql,
    u16* __restrict__ kh, u16* __restrict__ kl, u16* __restrict__ vt) {
    int w = threadIdx.x >> 6, lane = threadIdx.x & 63;
    int m0 = blockIdx.y * 128 + w * 32;
    int n0 = blockIdx.x * 64;                  // global col in [0,3072)
    int wi = n0 >> 10;                         // 0=q 1=k 2=v
    int nn0 = n0 & 1023;
    const u16* bhp = wth + ((size_t)wi << 20);
    const u16* blp = wtl + ((size_t)wi << 20);
    int lrow = lane & 15, lk8 = (lane >> 4) * 8, rbase = (lane >> 4) * 4;

    f32x4 acc[2][4];
#pragma unroll
    for (int mt = 0; mt < 2; mt++)
#pragma unroll
        for (int nt = 0; nt < 4; nt++) acc[mt][nt] = (f32x4)0.f;

    for (int k = 0; k < 1024; k += 32) {
        short8 amh[2], aml[2];
#pragma unroll
        for (int mt = 0; mt < 2; mt++) {
            size_t ao = (size_t)(m0 + mt * 16 + lrow) * 1024 + k + lk8;
            amh[mt] = *(const short8*)(xh + ao);
            aml[mt] = *(const short8*)(xl + ao);
        }
#pragma unroll
        for (int nt = 0; nt < 4; nt++) {
            size_t bo = (size_t)(nn0 + nt * 16 + lrow) * 1024 + k + lk8;
            short8 b_h = *(const short8*)(bhp + bo);
            short8 b_l = *(const short8*)(blp + bo);
#pragma unroll
            for (int mt = 0; mt < 2; mt++) {
                acc[mt][nt] = __builtin_amdgcn_mfma_f32_16x16x32_bf16(amh[mt], b_h, acc[mt][nt], 0, 0, 0);
                acc[mt][nt] = __builtin_amdgcn_mfma_f32_16x16x32_bf16(amh[mt], b_l, acc[mt][nt], 0, 0, 0);
                acc[mt][nt] = __builtin_amdgcn_mfma_f32_16x16x32_bf16(aml[mt], b_h, acc[mt][nt], 0, 0, 0);
            }
        }
    }

    const float* bias = (wi == 0) ? bq : (wi == 1) ? bk : bv;
#pragma unroll
    for (int mt = 0; mt < 2; mt++)
#pragma unroll
        for (int nt = 0; nt < 4; nt++) {
            int n = nn0 + nt * 16 + lrow;
            float bias_v = bias[n];
            int hh = n >> 6, c = n & 63;
#pragma unroll
            for (int j = 0; j < 4; j++) {
                int m = m0 + mt * 16 + rbase + j;
                float v = acc[mt][nt][j] + bias_v;
                int b = m >> 11, s = m & 2047;
                if (wi < 2) {
                    size_t idx = ((size_t)(b * NH + hh) * SEQ + s) * HD + c;
                    u16 hi = bf16_rne(v);
                    u16 lo = bf16_rne(v - bf16_to_f(hi));
                    if (wi == 0) { qh[idx] = hi; ql[idx] = lo; }
                    else         { kh[idx] = hi; kl[idx] = lo; }
                } else {
                    size_t idx = ((size_t)(b * NH + hh) * HD + c) * SEQ + s;
                    vt[idx] = bf16_rne(v);
                }
            }
        }
}

// ---------------- K2: fused attention (scores -> softmax -> attn write -> PV) ----------------
// One wg = one (b,h, 16-row Q tile). 4 waves, each owns 512 K-columns.
__global__ __launch_bounds__(256) void k_attn(
    const u16* __restrict__ qh, const u16* __restrict__ ql,
    const u16* __restrict__ kh, const u16* __restrict__ kl,
    const u16* __restrict__ vt, float* __restrict__ attn_out,
    u16* __restrict__ ch, u16* __restrict__ cl) {
    __shared__ float sm_m[4][16];
    __shared__ float sm_l[4][16];
    __shared__ u16 p_lds[4][16][40];      // 32 used + pad, 80B row stride (16B aligned)
    __shared__ float ctx_red[4][16][68];  // pad 64->68 to spread banks

    int w = threadIdx.x >> 6, lane = threadIdx.x & 63;
    int bid = blockIdx.x;
    int qt = bid & 127, bh = bid >> 7;    // bh = b*16+h
    int q0 = qt * 16;
    int lrow = lane & 15, lk8 = (lane >> 4) * 8, rbase = (lane >> 4) * 4;

    const u16* qhp = qh + (size_t)bh * SEQ * HD;
    const u16* qlp = ql + (size_t)bh * SEQ * HD;
    const u16* khp = kh + (size_t)bh * SEQ * HD;
    const u16* klp = kl + (size_t)bh * SEQ * HD;
    const u16* vtp = vt + (size_t)bh * HD * SEQ;

    // Q fragments (A operand), 2 k-steps covering hd=64
    short8 aqh[2], aql[2];
#pragma unroll
    for (int kk = 0; kk < 2; kk++) {
        size_t o = (size_t)(q0 + lrow) * HD + kk * 32 + lk8;
        aqh[kk] = *(const short8*)(qhp + o);
        aql[kk] = *(const short8*)(qlp + o);
    }

    f32x4 acc[32];
#pragma unroll
    for (int t = 0; t < 32; t++) acc[t] = (f32x4)0.f;

    int c0w = w * 512;
#pragma unroll
    for (int t = 0; t < 32; t++) {
        int col0 = c0w + t * 16;
#pragma unroll
        for (int kk = 0; kk < 2; kk++) {
            size_t o = (size_t)(col0 + lrow) * HD + kk * 32 + lk8;
            short8 bkh = *(const short8*)(khp + o);
            short8 bkl = *(const short8*)(klp + o);
            acc[t] = __builtin_amdgcn_mfma_f32_16x16x32_bf16(aqh[kk], bkh, acc[t], 0, 0, 0);
            acc[t] = __builtin_amdgcn_mfma_f32_16x16x32_bf16(aqh[kk], bkl, acc[t], 0, 0, 0);
            acc[t] = __builtin_amdgcn_mfma_f32_16x16x32_bf16(aql[kk], bkh, acc[t], 0, 0, 0);
        }
    }
    // scale by 1/sqrt(hd)
#pragma unroll
    for (int t = 0; t < 32; t++)
#pragma unroll
        for (int j = 0; j < 4; j++) acc[t][j] *= 0.125f;

    // row max (this wave's 512 cols), then cross-wave
    float mrow[4];
#pragma unroll
    for (int j = 0; j < 4; j++) {
        float m_ = acc[0][j];
#pragma unroll
        for (int t = 1; t < 32; t++) m_ = fmaxf(m_, acc[t][j]);
        for (int d = 1; d < 16; d <<= 1) m_ = fmaxf(m_, __shfl_xor(m_, d, 64));
        mrow[j] = m_;
    }
    if (lrow == 0) {
#pragma unroll
        for (int j = 0; j < 4; j++) sm_m[w][rbase + j] = mrow[j];
    }
    __syncthreads();
#pragma unroll
    for (int j = 0; j < 4; j++) {
        float M = sm_m[0][rbase + j];
#pragma unroll
        for (int w2 = 1; w2 < 4; w2++) M = fmaxf(M, sm_m[w2][rbase + j]);
        mrow[j] = M;
    }

    // exp + row sum
    float lsum[4];
#pragma unroll
    for (int j = 0; j < 4; j++) {
        float s_ = 0.f;
#pragma unroll
        for (int t = 0; t < 32; t++) {
            float e = expf(acc[t][j] - mrow[j]);
            acc[t][j] = e;
            s_ += e;
        }
        for (int d = 1; d < 16; d <<= 1) s_ += __shfl_xor(s_, d, 64);
        lsum[j] = s_;
    }
    if (lrow == 0) {
#pragma unroll
        for (int j = 0; j < 4; j++) sm_l[w][rbase + j] = lsum[j];
    }
    __syncthreads();
    float inv[4];
#pragma unroll
    for (int j = 0; j < 4; j++) {
        float L = sm_l[0][rbase + j] + sm_l[1][rbase + j] + sm_l[2][rbase + j] + sm_l[3][rbase + j];
        inv[j] = 1.f / L;
    }

    // normalize, write attn (fp32, exact output)
    float* attn_base = attn_out + ((size_t)bh * SEQ + q0) * SEQ;
#pragma unroll
    for (int t = 0; t < 32; t++) {
        int col = c0w + t * 16 + lrow;
#pragma unroll
        for (int j = 0; j < 4; j++) {
            float p = acc[t][j] * inv[j];
            acc[t][j] = p;
            attn_base[(size_t)(rbase + j) * SEQ + col] = p;
        }
    }

    // PV: ctx[16,64] partial over this wave's 512 cols
    f32x4 cacc[4];
#pragma unroll
    for (int nt = 0; nt < 4; nt++) cacc[nt] = (f32x4)0.f;
#pragma unroll
    for (int c2 = 0; c2 < 16; c2++) {
        // stage P[16,32] bf16 into this wave's LDS slab
#pragma unroll
        for (int tt = 0; tt < 2; tt++) {
            int t = c2 * 2 + tt;
#pragma unroll
            for (int j = 0; j < 4; j++)
                p_lds[w][rbase + j][tt * 16 + lrow] = bf16_rne(acc[t][j]);
        }
        short8 pf = *(const short8*)&p_lds[w][lrow][lk8];
        int s0 = c0w + c2 * 32;
#pragma unroll
        for (int nt = 0; nt < 4; nt++) {
            short8 vf = *(const short8*)(vtp + (size_t)(nt * 16 + lrow) * SEQ + s0 + lk8);
            cacc[nt] = __builtin_amdgcn_mfma_f32_16x16x32_bf16(pf, vf, cacc[nt], 0, 0, 0);
        }
    }

    // cross-wave ctx reduce + write ctx hi/lo (merged-head layout [B,S,D])
#pragma unroll
    for (int nt = 0; nt < 4; nt++)
#pragma unroll
        for (int j = 0; j < 4; j++)
            ctx_red[w][rbase + j][nt * 16 + lrow] = cacc[nt][j];
    __syncthreads();
    int b = bh >> 4, h = bh & 15;
    int e0 = threadIdx.x * 4;
#pragma unroll
    for (int q = 0; q < 4; q++) {
        int e = e0 + q;
        int r = e >> 6, c = e & 63;
        float s = ctx_red[0][r][c] + ctx_red[1][r][c] + ctx_red[2][r][c] + ctx_red[3][r][c];
        size_t idx = ((size_t)b * SEQ + q0 + r) * DM + h * HD + c;
        u16 hi = bf16_rne(s);
        ch[idx] = hi;
        cl[idx] = bf16_rne(s - bf16_to_f(hi));
    }
}

// ---------------- K3: output projection GEMM ----------------
__global__ __launch_bounds__(256) void k_gemm_out(
    const u16* __restrict__ ah, const u16* __restrict__ al,
    const u16* __restrict__ wth, const u16* __restrict__ wtl,
    const float* __restrict__ bo, float* __restrict__ out) {
    int w = threadIdx.x >> 6, lane = threadIdx.x & 63;
    int m0 = blockIdx.y * 128 + w * 32;
    int n0 = blockIdx.x * 64;
    const u16* bhp = wth + ((size_t)3 << 20);   // wo region
    const u16* blp = wtl + ((size_t)3 << 20);
    int lrow = lane & 15, lk8 = (lane >> 4) * 8, rbase = (lane >> 4) * 4;

    f32x4 acc[2][4];
#pragma unroll
    for (int mt = 0; mt < 2; mt++)
#pragma unroll
        for (int nt = 0; nt < 4; nt++) acc[mt][nt] = (f32x4)0.f;

    for (int k = 0; k < 1024; k += 32) {
        short8 amh[2], aml[2];
#pragma unroll
        for (int mt = 0; mt < 2; mt++) {
            size_t ao = (size_t)(m0 + mt * 16 + lrow) * 1024 + k + lk8;
            amh[mt] = *(const short8*)(ah + ao);
            aml[mt] = *(const short8*)(al + ao);
        }
#pragma unroll
        for (int nt = 0; nt < 4; nt++) {
            size_t bo_ = (size_t)(n0 + nt * 16 + lrow) * 1024 + k + lk8;
            short8 b_h = *(const short8*)(bhp + bo_);
            short8 b_l = *(const short8*)(blp + bo_);
#pragma unroll
            for (int mt = 0; mt < 2; mt++) {
                acc[mt][nt] = __builtin_amdgcn_mfma_f32_16x16x32_bf16(amh[mt], b_h, acc[mt][nt], 0, 0, 0);
                acc[mt][nt] = __builtin_amdgcn_mfma_f32_16x16x32_bf16(amh[mt], b_l, acc[mt][nt], 0, 0, 0);
                acc[mt][nt] = __builtin_amdgcn_mfma_f32_16x16x32_bf16(aml[mt], b_h, acc[mt][nt], 0, 0, 0);
            }
        }
    }
#pragma unroll
    for (int mt = 0; mt < 2; mt++)
#pragma unroll
        for (int nt = 0; nt < 4; nt++) {
            int n = n0 + nt * 16 + lrow;
            float bias_v = bo[n];
#pragma unroll
            for (int j = 0; j < 4; j++) {
                int m = m0 + mt * 16 + rbase + j;
                out[(size_t)m * 1024 + n] = acc[mt][nt][j] + bias_v;
            }
        }
}

extern "C" void kernel_launch(void* const* d_in, const int* in_sizes, int n_in,
                              void* d_out, int out_size, void* d_ws, size_t ws_size,
                              hipStream_t stream) {
    const float* x  = (const float*)d_in[0];
    const float* wq = (const float*)d_in[1];
    const float* bq = (const float*)d_in[2];
    const float* wk = (const float*)d_in[3];
    const float* bk = (const float*)d_in[4];
    const float* wv = (const float*)d_in[5];
    const float* bv = (const float*)d_in[6];
    const float* wo = (const float*)d_in[7];
    const float* bo = (const float*)d_in[8];

    float* out  = (float*)d_out;
    float* attn = out + (size_t)BATCH * SEQ * DM;

    char* ws = (char*)d_ws;
    const size_t MB = 1u << 20;
    u16* x_hi  = (u16*)(ws + 0 * MB);     // 16 MiB each half
    u16* x_lo  = (u16*)(ws + 16 * MB);
    u16* wt_hi = (u16*)(ws + 32 * MB);    // 8 MiB (4 weights, [n][k])
    u16* wt_lo = (u16*)(ws + 40 * MB);
    u16* q_hi  = (u16*)(ws + 48 * MB);
    u16* q_lo  = (u16*)(ws + 64 * MB);
    u16* k_hi  = (u16*)(ws + 80 * MB);
    u16* k_lo  = (u16*)(ws + 96 * MB);
    u16* vt    = (u16*)(ws + 112 * MB);   // ends at 128 MiB
    u16* c_hi  = x_hi;                    // reuse x region for ctx
    u16* c_lo  = x_lo;

    int n4 = BATCH * SEQ * DM / 4;
    k_split_x<<<(n4 + 255) / 256, 256, 0, stream>>>((const float4*)x, (ushort4*)x_hi, (ushort4*)x_lo, n4);
    k_split_w<<<4096, 256, 0, stream>>>(wq, wk, wv, wo, wt_hi, wt_lo);
    k_gemm_qkv<<<dim3(48, 64), 256, 0, stream>>>(x_hi, x_lo, wt_hi, wt_lo, bq, bk, bv,
                                                 q_hi, q_lo, k_hi, k_lo, vt);
    k_attn<<<BATCH * NH * (SEQ / 16), 256, 0, stream>>>(q_hi, q_lo, k_hi, k_lo, vt, attn, c_hi, c_lo);
    k_gemm_out<<<dim3(16, 64), 256, 0, stream>>>(c_hi, c_lo, wt_hi, wt_lo, bo, out);
}

// Round 2
// 1519.029 us; speedup vs baseline: 1.4164x; 1.4164x over previous
//
#include <hip/hip_runtime.h>
#include <hip/hip_bf16.h>
#include <stdint.h>

typedef __attribute__((ext_vector_type(8))) short short8;
typedef __attribute__((ext_vector_type(4))) float f32x4;
typedef unsigned short u16;

#define BATCH 4
#define NH    16
#define SEQ   2048
#define DM    1024
#define HD    64

__device__ __forceinline__ u16 bf16_rne(float f) {
    uint32_t u = __builtin_bit_cast(uint32_t, f);
    uint32_t r = (u + 0x7FFFu + ((u >> 16) & 1u)) >> 16;
    return (u16)r;
}
__device__ __forceinline__ float bf16_to_f(u16 h) {
    uint32_t u = ((uint32_t)h) << 16;
    return __builtin_bit_cast(float, u);
}

// ---------------- K0a: split x into bf16 hi/lo ----------------
__global__ void k_split_x(const float4* __restrict__ x, ushort4* __restrict__ xh,
                          ushort4* __restrict__ xl, int n4) {
    int i = blockIdx.x * 256 + threadIdx.x;
    if (i >= n4) return;
    float4 v = x[i];
    float f[4] = {v.x, v.y, v.z, v.w};
    ushort4 h, l;
    u16* hp = (u16*)&h; u16* lp = (u16*)&l;
#pragma unroll
    for (int j = 0; j < 4; j++) {
        u16 hh = bf16_rne(f[j]);
        hp[j] = hh;
        lp[j] = bf16_rne(f[j] - bf16_to_f(hh));
    }
    xh[i] = h; xl[i] = l;
}

// ---------------- K0b: transpose + split the 4 weight matrices ----------------
// out layout: wt[wi][n][k] (n-major), wi in {q,k,v,o}
__global__ void k_split_w(const float* __restrict__ w0, const float* __restrict__ w1,
                          const float* __restrict__ w2, const float* __restrict__ w3,
                          u16* __restrict__ wth, u16* __restrict__ wtl) {
    __shared__ float tile[32][33];
    int bx = blockIdx.x;
    int wi = bx >> 10;            // 1024 tiles per weight
    int t  = bx & 1023;
    int kt = t >> 5, nt = t & 31;
    const float* w = (wi == 0) ? w0 : (wi == 1) ? w1 : (wi == 2) ? w2 : w3;
    int tx = threadIdx.x & 31, ty = threadIdx.x >> 5;   // ty 0..7
#pragma unroll
    for (int i = 0; i < 4; i++) {
        int r = ty + i * 8;
        tile[r][tx] = w[(size_t)(kt * 32 + r) * 1024 + nt * 32 + tx];
    }
    __syncthreads();
    size_t base = ((size_t)wi << 20);
#pragma unroll
    for (int i = 0; i < 4; i++) {
        int r = ty + i * 8;
        float f = tile[tx][r];    // = w[kt*32+tx][nt*32+r]
        u16 h = bf16_rne(f);
        u16 l = bf16_rne(f - bf16_to_f(h));
        size_t dst = base + (size_t)(nt * 32 + r) * 1024 + kt * 32 + tx;
        wth[dst] = h; wtl[dst] = l;
    }
}

// ---------------- K1: QKV projection GEMM (split-bf16 MFMA) ----------------
// C[8192,3072] = X[8192,1024] @ [Wq|Wk|Wv]; writes q,k (hi/lo, [B,H,S,hd]) and v^T ([B,H,hd,S])
__global__ __launch_bounds__(256) void k_gemm_qkv(
    const u16* __restrict__ xh, const u16* __restrict__ xl,
    const u16* __restrict__ wth, const u16* __restrict__ wtl,
    const float* __restrict__ bq, const float* __restrict__ bk, const float* __restrict__ bv,
    u16* __restrict__ qh, u16* __restrict__ ql,
    u16* __restrict__ kh, u16* __restrict__ kl, u16* __restrict__ vt) {
    int w = threadIdx.x >> 6, lane = threadIdx.x & 63;
    int m0 = blockIdx.y * 128 + w * 32;
    int n0 = blockIdx.x * 64;                  // global col in [0,3072)
    int wi = n0 >> 10;                         // 0=q 1=k 2=v
    int nn0 = n0 & 1023;
    const u16* bhp = wth + ((size_t)wi << 20);
    const u16* blp = wtl + ((size_t)wi << 20);
    int lrow = lane & 15, lk8 = (lane >> 4) * 8, rbase = (lane >> 4) * 4;

    f32x4 acc[2][4];
#pragma unroll
    for (int mt = 0; mt < 2; mt++)
#pragma unroll
        for (int nt = 0; nt < 4; nt++) acc[mt][nt] = (f32x4)0.f;

    for (int k = 0; k < 1024; k += 32) {
        short8 amh[2], aml[2];
#pragma unroll
        for (int mt = 0; mt < 2; mt++) {
            size_t ao = (size_t)(m0 + mt * 16 + lrow) * 1024 + k + lk8;
            amh[mt] = *(const short8*)(xh + ao);
            aml[mt] = *(const short8*)(xl + ao);
        }
#pragma unroll
        for (int nt = 0; nt < 4; nt++) {
            size_t bo = (size_t)(nn0 + nt * 16 + lrow) * 1024 + k + lk8;
            short8 b_h = *(const short8*)(bhp + bo);
            short8 b_l = *(const short8*)(blp + bo);
#pragma unroll
            for (int mt = 0; mt < 2; mt++) {
                acc[mt][nt] = __builtin_amdgcn_mfma_f32_16x16x32_bf16(amh[mt], b_h, acc[mt][nt], 0, 0, 0);
                acc[mt][nt] = __builtin_amdgcn_mfma_f32_16x16x32_bf16(amh[mt], b_l, acc[mt][nt], 0, 0, 0);
                acc[mt][nt] = __builtin_amdgcn_mfma_f32_16x16x32_bf16(aml[mt], b_h, acc[mt][nt], 0, 0, 0);
            }
        }
    }

    const float* bias = (wi == 0) ? bq : (wi == 1) ? bk : bv;
#pragma unroll
    for (int mt = 0; mt < 2; mt++)
#pragma unroll
        for (int nt = 0; nt < 4; nt++) {
            int n = nn0 + nt * 16 + lrow;
            float bias_v = bias[n];
            int hh = n >> 6, c = n & 63;
#pragma unroll
            for (int j = 0; j < 4; j++) {
                int m = m0 + mt * 16 + rbase + j;
                float v = acc[mt][nt][j] + bias_v;
                int b = m >> 11, s = m & 2047;
                if (wi < 2) {
                    size_t idx = ((size_t)(b * NH + hh) * SEQ + s) * HD + c;
                    u16 hi = bf16_rne(v);
                    u16 lo = bf16_rne(v - bf16_to_f(hi));
                    if (wi == 0) { qh[idx] = hi; ql[idx] = lo; }
                    else         { kh[idx] = hi; kl[idx] = lo; }
                } else {
                    size_t idx = ((size_t)(b * NH + hh) * HD + c) * SEQ + s;
                    vt[idx] = bf16_rne(v);
                }
            }
        }
}

// ---------------- K2: fused attention (scores -> softmax -> attn write -> PV) ----------------
// One wg = one (b,h, 16-row Q tile). 8 waves, each owns 256 K-columns.
// __launch_bounds__(512,4): cap VGPRs at 128 -> 4 waves/SIMD for latency hiding.
#define NW 8
__global__ __launch_bounds__(512, 4) void k_attn(
    const u16* __restrict__ qh, const u16* __restrict__ ql,
    const u16* __restrict__ kh, const u16* __restrict__ kl,
    const u16* __restrict__ vt, float* __restrict__ attn_out,
    u16* __restrict__ ch, u16* __restrict__ cl) {
    __shared__ float sm_m[NW][16];
    __shared__ float sm_l[NW][16];
    __shared__ u16 p_lds[NW][16][40];      // 32 used + pad
    __shared__ float ctx_red[NW][16][68];  // pad 64->68 to spread banks

    int w = threadIdx.x >> 6, lane = threadIdx.x & 63;
    int bid = blockIdx.x;
    int qt = bid & 127, bh = bid >> 7;    // bh = b*16+h
    int q0 = qt * 16;
    int lrow = lane & 15, lk8 = (lane >> 4) * 8, rbase = (lane >> 4) * 4;

    const u16* qhp = qh + (size_t)bh * SEQ * HD;
    const u16* qlp = ql + (size_t)bh * SEQ * HD;
    const u16* khp = kh + (size_t)bh * SEQ * HD;
    const u16* klp = kl + (size_t)bh * SEQ * HD;
    const u16* vtp = vt + (size_t)bh * HD * SEQ;

    // Q fragments (A operand), 2 k-steps covering hd=64
    short8 aqh[2], aql[2];
#pragma unroll
    for (int kk = 0; kk < 2; kk++) {
        size_t o = (size_t)(q0 + lrow) * HD + kk * 32 + lk8;
        aqh[kk] = *(const short8*)(qhp + o);
        aql[kk] = *(const short8*)(qlp + o);
    }

    f32x4 acc[16];
#pragma unroll
    for (int t = 0; t < 16; t++) acc[t] = (f32x4)0.f;

    int c0w = w * 256;
    int laneoff = lrow * HD + lk8;
#pragma unroll
    for (int t = 0; t < 16; t++) {
        int col0 = c0w + t * 16;
        const u16* kbase_h = khp + (size_t)col0 * HD + laneoff;
        const u16* kbase_l = klp + (size_t)col0 * HD + laneoff;
#pragma unroll
        for (int kk = 0; kk < 2; kk++) {
            short8 bkh = *(const short8*)(kbase_h + kk * 32);
            short8 bkl = *(const short8*)(kbase_l + kk * 32);
            acc[t] = __builtin_amdgcn_mfma_f32_16x16x32_bf16(aqh[kk], bkh, acc[t], 0, 0, 0);
            acc[t] = __builtin_amdgcn_mfma_f32_16x16x32_bf16(aqh[kk], bkl, acc[t], 0, 0, 0);
            acc[t] = __builtin_amdgcn_mfma_f32_16x16x32_bf16(aql[kk], bkh, acc[t], 0, 0, 0);
        }
    }

    // row max over this wave's 256 cols (raw scores; scale folded into exp)
    float mrow[4];
#pragma unroll
    for (int j = 0; j < 4; j++) {
        float m_ = acc[0][j];
#pragma unroll
        for (int t = 1; t < 16; t++) m_ = fmaxf(m_, acc[t][j]);
        for (int d = 1; d < 16; d <<= 1) m_ = fmaxf(m_, __shfl_xor(m_, d, 64));
        mrow[j] = m_;
    }
    if (lrow == 0) {
#pragma unroll
        for (int j = 0; j < 4; j++) sm_m[w][rbase + j] = mrow[j];
    }
    __syncthreads();
#pragma unroll
    for (int j = 0; j < 4; j++) {
        float M = sm_m[0][rbase + j];
#pragma unroll
        for (int w2 = 1; w2 < NW; w2++) M = fmaxf(M, sm_m[w2][rbase + j]);
        mrow[j] = M;
    }

    // exp + row sum; exp(0.125*(s-m)) == exp2(C*(s-m))
    const float C = 0.125f * 1.44269504088896f;
    float lsum[4];
#pragma unroll
    for (int j = 0; j < 4; j++) {
        float s_ = 0.f;
#pragma unroll
        for (int t = 0; t < 16; t++) {
            float e = exp2f((acc[t][j] - mrow[j]) * C);
            acc[t][j] = e;
            s_ += e;
        }
        for (int d = 1; d < 16; d <<= 1) s_ += __shfl_xor(s_, d, 64);
        lsum[j] = s_;
    }
    if (lrow == 0) {
#pragma unroll
        for (int j = 0; j < 4; j++) sm_l[w][rbase + j] = lsum[j];
    }
    __syncthreads();
    float inv[4];
#pragma unroll
    for (int j = 0; j < 4; j++) {
        float L = 0.f;
#pragma unroll
        for (int w2 = 0; w2 < NW; w2++) L += sm_l[w2][rbase + j];
        inv[j] = 1.f / L;
    }

    // normalize, write attn (fp32, nontemporal — streaming output, keep L2 for K/V)
    float* attn_base = attn_out + ((size_t)bh * SEQ + q0) * SEQ;
#pragma unroll
    for (int t = 0; t < 16; t++) {
        int col = c0w + t * 16 + lrow;
#pragma unroll
        for (int j = 0; j < 4; j++) {
            float p = acc[t][j] * inv[j];
            acc[t][j] = p;
            __builtin_nontemporal_store(p, &attn_base[(size_t)(rbase + j) * SEQ + col]);
        }
    }

    // PV: ctx[16,64] partial over this wave's 256 cols
    f32x4 cacc[4];
#pragma unroll
    for (int nt = 0; nt < 4; nt++) cacc[nt] = (f32x4)0.f;
#pragma unroll
    for (int c2 = 0; c2 < 8; c2++) {
        // stage P[16,32] bf16 into this wave's LDS slab
#pragma unroll
        for (int tt = 0; tt < 2; tt++) {
            int t = c2 * 2 + tt;
#pragma unroll
            for (int j = 0; j < 4; j++)
                p_lds[w][rbase + j][tt * 16 + lrow] = bf16_rne(acc[t][j]);
        }
        short8 pf = *(const short8*)&p_lds[w][lrow][lk8];
        int s0 = c0w + c2 * 32;
#pragma unroll
        for (int nt = 0; nt < 4; nt++) {
            short8 vf = *(const short8*)(vtp + (size_t)(nt * 16 + lrow) * SEQ + s0 + lk8);
            cacc[nt] = __builtin_amdgcn_mfma_f32_16x16x32_bf16(pf, vf, cacc[nt], 0, 0, 0);
        }
    }

    // cross-wave ctx reduce + write ctx hi/lo (merged-head layout [B,S,D])
#pragma unroll
    for (int nt = 0; nt < 4; nt++)
#pragma unroll
        for (int j = 0; j < 4; j++)
            ctx_red[w][rbase + j][nt * 16 + lrow] = cacc[nt][j];
    __syncthreads();
    int b = bh >> 4, h = bh & 15;
    int e0 = threadIdx.x * 2;
#pragma unroll
    for (int q = 0; q < 2; q++) {
        int e = e0 + q;
        int r = e >> 6, c = e & 63;
        float s = 0.f;
#pragma unroll
        for (int w2 = 0; w2 < NW; w2++) s += ctx_red[w2][r][c];
        size_t idx = ((size_t)b * SEQ + q0 + r) * DM + h * HD + c;
        u16 hi = bf16_rne(s);
        ch[idx] = hi;
        cl[idx] = bf16_rne(s - bf16_to_f(hi));
    }
}

// ---------------- K3: output projection GEMM ----------------
__global__ __launch_bounds__(256) void k_gemm_out(
    const u16* __restrict__ ah, const u16* __restrict__ al,
    const u16* __restrict__ wth, const u16* __restrict__ wtl,
    const float* __restrict__ bo, float* __restrict__ out) {
    int w = threadIdx.x >> 6, lane = threadIdx.x & 63;
    int m0 = blockIdx.y * 128 + w * 32;
    int n0 = blockIdx.x * 64;
    const u16* bhp = wth + ((size_t)3 << 20);   // wo region
    const u16* blp = wtl + ((size_t)3 << 20);
    int lrow = lane & 15, lk8 = (lane >> 4) * 8, rbase = (lane >> 4) * 4;

    f32x4 acc[2][4];
#pragma unroll
    for (int mt = 0; mt < 2; mt++)
#pragma unroll
        for (int nt = 0; nt < 4; nt++) acc[mt][nt] = (f32x4)0.f;

    for (int k = 0; k < 1024; k += 32) {
        short8 amh[2], aml[2];
#pragma unroll
        for (int mt = 0; mt < 2; mt++) {
            size_t ao = (size_t)(m0 + mt * 16 + lrow) * 1024 + k + lk8;
            amh[mt] = *(const short8*)(ah + ao);
            aml[mt] = *(const short8*)(al + ao);
        }
#pragma unroll
        for (int nt = 0; nt < 4; nt++) {
            size_t bo_ = (size_t)(n0 + nt * 16 + lrow) * 1024 + k + lk8;
            short8 b_h = *(const short8*)(bhp + bo_);
            short8 b_l = *(const short8*)(blp + bo_);
#pragma unroll
            for (int mt = 0; mt < 2; mt++) {
                acc[mt][nt] = __builtin_amdgcn_mfma_f32_16x16x32_bf16(amh[mt], b_h, acc[mt][nt], 0, 0, 0);
                acc[mt][nt] = __builtin_amdgcn_mfma_f32_16x16x32_bf16(amh[mt], b_l, acc[mt][nt], 0, 0, 0);
                acc[mt][nt] = __builtin_amdgcn_mfma_f32_16x16x32_bf16(aml[mt], b_h, acc[mt][nt], 0, 0, 0);
            }
        }
    }
#pragma unroll
    for (int mt = 0; mt < 2; mt++)
#pragma unroll
        for (int nt = 0; nt < 4; nt++) {
            int n = n0 + nt * 16 + lrow;
            float bias_v = bo[n];
#pragma unroll
            for (int j = 0; j < 4; j++) {
                int m = m0 + mt * 16 + rbase + j;
                out[(size_t)m * 1024 + n] = acc[mt][nt][j] + bias_v;
            }
        }
}

extern "C" void kernel_launch(void* const* d_in, const int* in_sizes, int n_in,
                              void* d_out, int out_size, void* d_ws, size_t ws_size,
                              hipStream_t stream) {
    const float* x  = (const float*)d_in[0];
    const float* wq = (const float*)d_in[1];
    const float* bq = (const float*)d_in[2];
    const float* wk = (const float*)d_in[3];
    const float* bk = (const float*)d_in[4];
    const float* wv = (const float*)d_in[5];
    const float* bv = (const float*)d_in[6];
    const float* wo = (const float*)d_in[7];
    const float* bo = (const float*)d_in[8];

    float* out  = (float*)d_out;
    float* attn = out + (size_t)BATCH * SEQ * DM;

    char* ws = (char*)d_ws;
    const size_t MB = 1u << 20;
    u16* x_hi  = (u16*)(ws + 0 * MB);     // 16 MiB each half
    u16* x_lo  = (u16*)(ws + 16 * MB);
    u16* wt_hi = (u16*)(ws + 32 * MB);    // 8 MiB (4 weights, [n][k])
    u16* wt_lo = (u16*)(ws + 40 * MB);
    u16* q_hi  = (u16*)(ws + 48 * MB);
    u16* q_lo  = (u16*)(ws + 64 * MB);
    u16* k_hi  = (u16*)(ws + 80 * MB);
    u16* k_lo  = (u16*)(ws + 96 * MB);
    u16* vt    = (u16*)(ws + 112 * MB);   // ends at 128 MiB
    u16* c_hi  = x_hi;                    // reuse x region for ctx
    u16* c_lo  = x_lo;

    int n4 = BATCH * SEQ * DM / 4;
    k_split_x<<<(n4 + 255) / 256, 256, 0, stream>>>((const float4*)x, (ushort4*)x_hi, (ushort4*)x_lo, n4);
    k_split_w<<<4096, 256, 0, stream>>>(wq, wk, wv, wo, wt_hi, wt_lo);
    k_gemm_qkv<<<dim3(48, 64), 256, 0, stream>>>(x_hi, x_lo, wt_hi, wt_lo, bq, bk, bv,
                                                 q_hi, q_lo, k_hi, k_lo, vt);
    k_attn<<<BATCH * NH * (SEQ / 16), 512, 0, stream>>>(q_hi, q_lo, k_hi, k_lo, vt, attn, c_hi, c_lo);
    k_gemm_out<<<dim3(16, 64), 256, 0, stream>>>(c_hi, c_lo, wt_hi, wt_lo, bo, out);
}

// Round 3
// 1329.946 us; speedup vs baseline: 1.6178x; 1.1422x over previous
//
#include <hip/hip_runtime.h>
#include <hip/hip_bf16.h>
#include <stdint.h>

typedef __attribute__((ext_vector_type(8))) short short8;
typedef __attribute__((ext_vector_type(4))) float f32x4;
typedef unsigned short u16;

#define BATCH 4
#define NH    16
#define SEQ   2048
#define DM    1024
#define HD    64

__device__ __forceinline__ u16 bf16_rne(float f) {
    uint32_t u = __builtin_bit_cast(uint32_t, f);
    uint32_t r = (u + 0x7FFFu + ((u >> 16) & 1u)) >> 16;
    return (u16)r;
}
__device__ __forceinline__ float bf16_to_f(u16 h) {
    uint32_t u = ((uint32_t)h) << 16;
    return __builtin_bit_cast(float, u);
}
__device__ __forceinline__ u16 f32_to_f16(float f) {
    _Float16 h = (_Float16)f;
    return __builtin_bit_cast(unsigned short, h);
}
__device__ __forceinline__ float f16_to_f32(u16 u) {
    _Float16 h = __builtin_bit_cast(_Float16, u);
    return (float)h;
}

// ---------------- K0a: split x into bf16 hi/lo ----------------
__global__ void k_split_x(const float4* __restrict__ x, ushort4* __restrict__ xh,
                          ushort4* __restrict__ xl, int n4) {
    int i = blockIdx.x * 256 + threadIdx.x;
    if (i >= n4) return;
    float4 v = x[i];
    float f[4] = {v.x, v.y, v.z, v.w};
    ushort4 h, l;
    u16* hp = (u16*)&h; u16* lp = (u16*)&l;
#pragma unroll
    for (int j = 0; j < 4; j++) {
        u16 hh = bf16_rne(f[j]);
        hp[j] = hh;
        lp[j] = bf16_rne(f[j] - bf16_to_f(hh));
    }
    xh[i] = h; xl[i] = l;
}

// ---------------- K0b: transpose + split the 4 weight matrices ----------------
__global__ void k_split_w(const float* __restrict__ w0, const float* __restrict__ w1,
                          const float* __restrict__ w2, const float* __restrict__ w3,
                          u16* __restrict__ wth, u16* __restrict__ wtl) {
    __shared__ float tile[32][33];
    int bx = blockIdx.x;
    int wi = bx >> 10;
    int t  = bx & 1023;
    int kt = t >> 5, nt = t & 31;
    const float* w = (wi == 0) ? w0 : (wi == 1) ? w1 : (wi == 2) ? w2 : w3;
    int tx = threadIdx.x & 31, ty = threadIdx.x >> 5;
#pragma unroll
    for (int i = 0; i < 4; i++) {
        int r = ty + i * 8;
        tile[r][tx] = w[(size_t)(kt * 32 + r) * 1024 + nt * 32 + tx];
    }
    __syncthreads();
    size_t base = ((size_t)wi << 20);
#pragma unroll
    for (int i = 0; i < 4; i++) {
        int r = ty + i * 8;
        float f = tile[tx][r];
        u16 h = bf16_rne(f);
        u16 l = bf16_rne(f - bf16_to_f(h));
        size_t dst = base + (size_t)(nt * 32 + r) * 1024 + kt * 32 + tx;
        wth[dst] = h; wtl[dst] = l;
    }
}

// ---------------- K1: QKV projection GEMM (split-bf16 MFMA) ----------------
// writes q (fp16 hi/lo, [B,H,S,hd]), k (fp16, [B,H,S,hd]), v^T (fp16, [B,H,hd,S])
__global__ __launch_bounds__(256, 4) void k_gemm_qkv(
    const u16* __restrict__ xh, const u16* __restrict__ xl,
    const u16* __restrict__ wth, const u16* __restrict__ wtl,
    const float* __restrict__ bq, const float* __restrict__ bk, const float* __restrict__ bv,
    u16* __restrict__ qh, u16* __restrict__ ql,
    u16* __restrict__ kf, u16* __restrict__ vt) {
    int w = threadIdx.x >> 6, lane = threadIdx.x & 63;
    // XCD-chunked swizzle: 3072 wgs, 8 XCDs, 384/XCD
    int lin = blockIdx.y * 48 + blockIdx.x;
    int lin2 = (lin & 7) * 384 + (lin >> 3);
    int bx = lin2 % 48, by = lin2 / 48;
    int m0 = by * 128 + w * 32;
    int n0 = bx * 64;
    int wi = n0 >> 10;
    int nn0 = n0 & 1023;
    const u16* bhp = wth + ((size_t)wi << 20);
    const u16* blp = wtl + ((size_t)wi << 20);
    int lrow = lane & 15, lk8 = (lane >> 4) * 8, rbase = (lane >> 4) * 4;

    f32x4 acc[2][4];
#pragma unroll
    for (int mt = 0; mt < 2; mt++)
#pragma unroll
        for (int nt = 0; nt < 4; nt++) acc[mt][nt] = (f32x4)0.f;

    for (int k = 0; k < 1024; k += 32) {
        short8 amh[2], aml[2];
#pragma unroll
        for (int mt = 0; mt < 2; mt++) {
            size_t ao = (size_t)(m0 + mt * 16 + lrow) * 1024 + k + lk8;
            amh[mt] = *(const short8*)(xh + ao);
            aml[mt] = *(const short8*)(xl + ao);
        }
#pragma unroll
        for (int nt = 0; nt < 4; nt++) {
            size_t bo = (size_t)(nn0 + nt * 16 + lrow) * 1024 + k + lk8;
            short8 b_h = *(const short8*)(bhp + bo);
            short8 b_l = *(const short8*)(blp + bo);
#pragma unroll
            for (int mt = 0; mt < 2; mt++) {
                acc[mt][nt] = __builtin_amdgcn_mfma_f32_16x16x32_bf16(amh[mt], b_h, acc[mt][nt], 0, 0, 0);
                acc[mt][nt] = __builtin_amdgcn_mfma_f32_16x16x32_bf16(amh[mt], b_l, acc[mt][nt], 0, 0, 0);
                acc[mt][nt] = __builtin_amdgcn_mfma_f32_16x16x32_bf16(aml[mt], b_h, acc[mt][nt], 0, 0, 0);
            }
        }
    }

    const float* bias = (wi == 0) ? bq : (wi == 1) ? bk : bv;
#pragma unroll
    for (int mt = 0; mt < 2; mt++)
#pragma unroll
        for (int nt = 0; nt < 4; nt++) {
            int n = nn0 + nt * 16 + lrow;
            float bias_v = bias[n];
            int hh = n >> 6, c = n & 63;
#pragma unroll
            for (int j = 0; j < 4; j++) {
                int m = m0 + mt * 16 + rbase + j;
                float v = acc[mt][nt][j] + bias_v;
                int b = m >> 11, s = m & 2047;
                if (wi == 0) {
                    size_t idx = ((size_t)(b * NH + hh) * SEQ + s) * HD + c;
                    u16 hi = f32_to_f16(v);
                    qh[idx] = hi;
                    ql[idx] = f32_to_f16(v - f16_to_f32(hi));
                } else if (wi == 1) {
                    size_t idx = ((size_t)(b * NH + hh) * SEQ + s) * HD + c;
                    kf[idx] = f32_to_f16(v);
                } else {
                    size_t idx = ((size_t)(b * NH + hh) * HD + c) * SEQ + s;
                    vt[idx] = f32_to_f16(v);
                }
            }
        }
}

// ---------------- K2: fused attention ----------------
// One wg = one (b,h, 16-row Q tile). 8 waves, each owns 256 K-columns. fp16 QK^T/PV.
#define NW 8
__global__ __launch_bounds__(512, 4) void k_attn(
    const u16* __restrict__ qh, const u16* __restrict__ ql,
    const u16* __restrict__ kf, const u16* __restrict__ vt,
    float* __restrict__ attn_out, u16* __restrict__ ch, u16* __restrict__ cl) {
    __shared__ float sm_m[NW][16];
    __shared__ float sm_l[NW][16];
    __shared__ u16 p_lds[NW][16][40];
    __shared__ float ctx_red[NW][16][68];

    int w = threadIdx.x >> 6, lane = threadIdx.x & 63;
    // XCD-chunked swizzle: 8192 wgs -> 1024/XCD = 8 heads/XCD (K/V L2 reuse)
    int bid0 = blockIdx.x;
    int bid = (bid0 & 7) * 1024 + (bid0 >> 3);
    int qt = bid & 127, bh = bid >> 7;
    int q0 = qt * 16;
    int lrow = lane & 15, lk8 = (lane >> 4) * 8, rbase = (lane >> 4) * 4;

    const u16* qhp = qh + (size_t)bh * SEQ * HD;
    const u16* qlp = ql + (size_t)bh * SEQ * HD;
    const u16* kfp = kf + (size_t)bh * SEQ * HD;
    const u16* vtp = vt + (size_t)bh * HD * SEQ;

    // Q fragments fp16 hi/lo, 2 k-steps covering hd=64
    short8 aqh[2], aql[2];
#pragma unroll
    for (int kk = 0; kk < 2; kk++) {
        size_t o = (size_t)(q0 + lrow) * HD + kk * 32 + lk8;
        aqh[kk] = *(const short8*)(qhp + o);
        aql[kk] = *(const short8*)(qlp + o);
    }

    f32x4 acc[16];
#pragma unroll
    for (int t = 0; t < 16; t++) acc[t] = (f32x4)0.f;

    int c0w = w * 256;
    int laneoff = lrow * HD + lk8;
#pragma unroll
    for (int t = 0; t < 16; t++) {
        int col0 = c0w + t * 16;
        const u16* kbase = kfp + (size_t)col0 * HD + laneoff;
#pragma unroll
        for (int kk = 0; kk < 2; kk++) {
            short8 bk_ = *(const short8*)(kbase + kk * 32);
            acc[t] = __builtin_amdgcn_mfma_f32_16x16x32_f16(aqh[kk], bk_, acc[t], 0, 0, 0);
            acc[t] = __builtin_amdgcn_mfma_f32_16x16x32_f16(aql[kk], bk_, acc[t], 0, 0, 0);
        }
    }

    // row max over this wave's 256 cols
    float mrow[4];
#pragma unroll
    for (int j = 0; j < 4; j++) {
        float m_ = acc[0][j];
#pragma unroll
        for (int t = 1; t < 16; t++) m_ = fmaxf(m_, acc[t][j]);
        for (int d = 1; d < 16; d <<= 1) m_ = fmaxf(m_, __shfl_xor(m_, d, 64));
        mrow[j] = m_;
    }
    if (lrow == 0) {
#pragma unroll
        for (int j = 0; j < 4; j++) sm_m[w][rbase + j] = mrow[j];
    }
    __syncthreads();
#pragma unroll
    for (int j = 0; j < 4; j++) {
        float M = sm_m[0][rbase + j];
#pragma unroll
        for (int w2 = 1; w2 < NW; w2++) M = fmaxf(M, sm_m[w2][rbase + j]);
        mrow[j] = M;
    }

    // exp + row sum; exp(0.125*(s-m)) == exp2(C*(s-m))
    const float C = 0.125f * 1.44269504088896f;
    float lsum[4];
#pragma unroll
    for (int j = 0; j < 4; j++) {
        float s_ = 0.f;
#pragma unroll
        for (int t = 0; t < 16; t++) {
            float e = exp2f((acc[t][j] - mrow[j]) * C);
            acc[t][j] = e;
            s_ += e;
        }
        for (int d = 1; d < 16; d <<= 1) s_ += __shfl_xor(s_, d, 64);
        lsum[j] = s_;
    }
    if (lrow == 0) {
#pragma unroll
        for (int j = 0; j < 4; j++) sm_l[w][rbase + j] = lsum[j];
    }
    __syncthreads();
    float inv[4];
#pragma unroll
    for (int j = 0; j < 4; j++) {
        float L = 0.f;
#pragma unroll
        for (int w2 = 0; w2 < NW; w2++) L += sm_l[w2][rbase + j];
        inv[j] = 1.f / L;
    }

    // normalize + write attn (fp32)
    float* attn_base = attn_out + ((size_t)bh * SEQ + q0) * SEQ;
#pragma unroll
    for (int t = 0; t < 16; t++) {
        int col = c0w + t * 16 + lrow;
#pragma unroll
        for (int j = 0; j < 4; j++) {
            float p = acc[t][j] * inv[j];
            acc[t][j] = p;
            attn_base[(size_t)(rbase + j) * SEQ + col] = p;
        }
    }

    // PV over this wave's 256 cols (P, V fp16)
    f32x4 cacc[4];
#pragma unroll
    for (int nt = 0; nt < 4; nt++) cacc[nt] = (f32x4)0.f;
#pragma unroll
    for (int c2 = 0; c2 < 8; c2++) {
#pragma unroll
        for (int tt = 0; tt < 2; tt++) {
            int t = c2 * 2 + tt;
#pragma unroll
            for (int j = 0; j < 4; j++)
                p_lds[w][rbase + j][tt * 16 + lrow] = f32_to_f16(acc[t][j]);
        }
        short8 pf = *(const short8*)&p_lds[w][lrow][lk8];
        int s0 = c0w + c2 * 32;
#pragma unroll
        for (int nt = 0; nt < 4; nt++) {
            short8 vf = *(const short8*)(vtp + (size_t)(nt * 16 + lrow) * SEQ + s0 + lk8);
            cacc[nt] = __builtin_amdgcn_mfma_f32_16x16x32_f16(pf, vf, cacc[nt], 0, 0, 0);
        }
    }

    // cross-wave ctx reduce + write ctx hi/lo bf16 ([B,S,D])
#pragma unroll
    for (int nt = 0; nt < 4; nt++)
#pragma unroll
        for (int j = 0; j < 4; j++)
            ctx_red[w][rbase + j][nt * 16 + lrow] = cacc[nt][j];
    __syncthreads();
    int b = bh >> 4, h = bh & 15;
    int e0 = threadIdx.x * 2;
#pragma unroll
    for (int q = 0; q < 2; q++) {
        int e = e0 + q;
        int r = e >> 6, c = e & 63;
        float s = 0.f;
#pragma unroll
        for (int w2 = 0; w2 < NW; w2++) s += ctx_red[w2][r][c];
        size_t idx = ((size_t)b * SEQ + q0 + r) * DM + h * HD + c;
        u16 hi = bf16_rne(s);
        ch[idx] = hi;
        cl[idx] = bf16_rne(s - bf16_to_f(hi));
    }
}

// ---------------- K3: output projection GEMM ----------------
__global__ __launch_bounds__(256, 4) void k_gemm_out(
    const u16* __restrict__ ah, const u16* __restrict__ al,
    const u16* __restrict__ wth, const u16* __restrict__ wtl,
    const float* __restrict__ bo, float* __restrict__ out) {
    int w = threadIdx.x >> 6, lane = threadIdx.x & 63;
    // XCD-chunked swizzle: 1024 wgs, 128/XCD
    int lin = blockIdx.y * 16 + blockIdx.x;
    int lin2 = (lin & 7) * 128 + (lin >> 3);
    int bx = lin2 % 16, by = lin2 / 16;
    int m0 = by * 128 + w * 32;
    int n0 = bx * 64;
    const u16* bhp = wth + ((size_t)3 << 20);
    const u16* blp = wtl + ((size_t)3 << 20);
    int lrow = lane & 15, lk8 = (lane >> 4) * 8, rbase = (lane >> 4) * 4;

    f32x4 acc[2][4];
#pragma unroll
    for (int mt = 0; mt < 2; mt++)
#pragma unroll
        for (int nt = 0; nt < 4; nt++) acc[mt][nt] = (f32x4)0.f;

    for (int k = 0; k < 1024; k += 32) {
        short8 amh[2], aml[2];
#pragma unroll
        for (int mt = 0; mt < 2; mt++) {
            size_t ao = (size_t)(m0 + mt * 16 + lrow) * 1024 + k + lk8;
            amh[mt] = *(const short8*)(ah + ao);
            aml[mt] = *(const short8*)(al + ao);
        }
#pragma unroll
        for (int nt = 0; nt < 4; nt++) {
            size_t bo_ = (size_t)(n0 + nt * 16 + lrow) * 1024 + k + lk8;
            short8 b_h = *(const short8*)(bhp + bo_);
            short8 b_l = *(const short8*)(blp + bo_);
#pragma unroll
            for (int mt = 0; mt < 2; mt++) {
                acc[mt][nt] = __builtin_amdgcn_mfma_f32_16x16x32_bf16(amh[mt], b_h, acc[mt][nt], 0, 0, 0);
                acc[mt][nt] = __builtin_amdgcn_mfma_f32_16x16x32_bf16(amh[mt], b_l, acc[mt][nt], 0, 0, 0);
                acc[mt][nt] = __builtin_amdgcn_mfma_f32_16x16x32_bf16(aml[mt], b_h, acc[mt][nt], 0, 0, 0);
            }
        }
    }
#pragma unroll
    for (int mt = 0; mt < 2; mt++)
#pragma unroll
        for (int nt = 0; nt < 4; nt++) {
            int n = n0 + nt * 16 + lrow;
            float bias_v = bo[n];
#pragma unroll
            for (int j = 0; j < 4; j++) {
                int m = m0 + mt * 16 + rbase + j;
                out[(size_t)m * 1024 + n] = acc[mt][nt][j] + bias_v;
            }
        }
}

extern "C" void kernel_launch(void* const* d_in, const int* in_sizes, int n_in,
                              void* d_out, int out_size, void* d_ws, size_t ws_size,
                              hipStream_t stream) {
    const float* x  = (const float*)d_in[0];
    const float* wq = (const float*)d_in[1];
    const float* bq = (const float*)d_in[2];
    const float* wk = (const float*)d_in[3];
    const float* bk = (const float*)d_in[4];
    const float* wv = (const float*)d_in[5];
    const float* bv = (const float*)d_in[6];
    const float* wo = (const float*)d_in[7];
    const float* bo = (const float*)d_in[8];

    float* out  = (float*)d_out;
    float* attn = out + (size_t)BATCH * SEQ * DM;

    char* ws = (char*)d_ws;
    const size_t MB = 1u << 20;
    u16* x_hi  = (u16*)(ws + 0 * MB);
    u16* x_lo  = (u16*)(ws + 16 * MB);
    u16* wt_hi = (u16*)(ws + 32 * MB);
    u16* wt_lo = (u16*)(ws + 40 * MB);
    u16* q_hi  = (u16*)(ws + 48 * MB);
    u16* q_lo  = (u16*)(ws + 64 * MB);
    u16* kf    = (u16*)(ws + 80 * MB);
    u16* vt    = (u16*)(ws + 96 * MB);
    u16* c_hi  = x_hi;                    // reuse x region for ctx
    u16* c_lo  = x_lo;

    int n4 = BATCH * SEQ * DM / 4;
    k_split_x<<<(n4 + 255) / 256, 256, 0, stream>>>((const float4*)x, (ushort4*)x_hi, (ushort4*)x_lo, n4);
    k_split_w<<<4096, 256, 0, stream>>>(wq, wk, wv, wo, wt_hi, wt_lo);
    k_gemm_qkv<<<dim3(48, 64), 256, 0, stream>>>(x_hi, x_lo, wt_hi, wt_lo, bq, bk, bv,
                                                 q_hi, q_lo, kf, vt);
    k_attn<<<BATCH * NH * (SEQ / 16), 512, 0, stream>>>(q_hi, q_lo, kf, vt, attn, c_hi, c_lo);
    k_gemm_out<<<dim3(16, 64), 256, 0, stream>>>(c_hi, c_lo, wt_hi, wt_lo, bo, out);
}

// Round 4
// 972.031 us; speedup vs baseline: 2.2135x; 1.3682x over previous
//
#include <hip/hip_runtime.h>
#include <hip/hip_bf16.h>
#include <stdint.h>

typedef __attribute__((ext_vector_type(8))) short short8;
typedef __attribute__((ext_vector_type(4))) float f32x4;
typedef unsigned short u16;

#define BATCH 4
#define NH    16
#define SEQ   2048
#define DM    1024
#define HD    64

__device__ __forceinline__ u16 f32_to_f16(float f) {
    _Float16 h = (_Float16)f;
    return __builtin_bit_cast(unsigned short, h);
}
__device__ __forceinline__ float f16_to_f32(u16 u) {
    _Float16 h = __builtin_bit_cast(_Float16, u);
    return (float)h;
}

// ---------------- K0a: convert x to fp16 ----------------
__global__ void k_split_x(const float4* __restrict__ x, ushort4* __restrict__ xf, int n4) {
    int i = blockIdx.x * 256 + threadIdx.x;
    if (i >= n4) return;
    float4 v = x[i];
    float f[4] = {v.x, v.y, v.z, v.w};
    ushort4 h;
    u16* hp = (u16*)&h;
#pragma unroll
    for (int j = 0; j < 4; j++) hp[j] = f32_to_f16(f[j]);
    xf[i] = h;
}

// ---------------- K0b: transpose + convert the 4 weight matrices to fp16 ----------------
// out layout: wt[wi][n][k] (n-major), wi in {q,k,v,o}
__global__ void k_split_w(const float* __restrict__ w0, const float* __restrict__ w1,
                          const float* __restrict__ w2, const float* __restrict__ w3,
                          u16* __restrict__ wt) {
    __shared__ float tile[32][33];
    int bx = blockIdx.x;
    int wi = bx >> 10;
    int t  = bx & 1023;
    int kt = t >> 5, nt = t & 31;
    const float* w = (wi == 0) ? w0 : (wi == 1) ? w1 : (wi == 2) ? w2 : w3;
    int tx = threadIdx.x & 31, ty = threadIdx.x >> 5;
#pragma unroll
    for (int i = 0; i < 4; i++) {
        int r = ty + i * 8;
        tile[r][tx] = w[(size_t)(kt * 32 + r) * 1024 + nt * 32 + tx];
    }
    __syncthreads();
    size_t base = ((size_t)wi << 20);
#pragma unroll
    for (int i = 0; i < 4; i++) {
        int r = ty + i * 8;
        size_t dst = base + (size_t)(nt * 32 + r) * 1024 + kt * 32 + tx;
        wt[dst] = f32_to_f16(tile[tx][r]);
    }
}

// ---------------- K1: QKV projection GEMM (single fp16 MFMA) ----------------
// writes q (fp16, [B,H,S,hd]), k (fp16, [B,H,S,hd]), v^T (fp16, [B,H,hd,S])
__global__ __launch_bounds__(256, 4) void k_gemm_qkv(
    const u16* __restrict__ xf, const u16* __restrict__ wt,
    const float* __restrict__ bq, const float* __restrict__ bk, const float* __restrict__ bv,
    u16* __restrict__ qf, u16* __restrict__ kf, u16* __restrict__ vt) {
    int w = threadIdx.x >> 6, lane = threadIdx.x & 63;
    // XCD-chunked swizzle: 3072 wgs, 8 XCDs, 384/XCD
    int lin = blockIdx.y * 48 + blockIdx.x;
    int lin2 = (lin & 7) * 384 + (lin >> 3);
    int bx = lin2 % 48, by = lin2 / 48;
    int m0 = by * 128 + w * 32;
    int n0 = bx * 64;
    int wi = n0 >> 10;
    int nn0 = n0 & 1023;
    const u16* bhp = wt + ((size_t)wi << 20);
    int lrow = lane & 15, lk8 = (lane >> 4) * 8, rbase = (lane >> 4) * 4;

    f32x4 acc[2][4];
#pragma unroll
    for (int mt = 0; mt < 2; mt++)
#pragma unroll
        for (int nt = 0; nt < 4; nt++) acc[mt][nt] = (f32x4)0.f;

    for (int k = 0; k < 1024; k += 32) {
        short8 am[2];
#pragma unroll
        for (int mt = 0; mt < 2; mt++) {
            size_t ao = (size_t)(m0 + mt * 16 + lrow) * 1024 + k + lk8;
            am[mt] = *(const short8*)(xf + ao);
        }
#pragma unroll
        for (int nt = 0; nt < 4; nt++) {
            size_t bo = (size_t)(nn0 + nt * 16 + lrow) * 1024 + k + lk8;
            short8 b_h = *(const short8*)(bhp + bo);
#pragma unroll
            for (int mt = 0; mt < 2; mt++)
                acc[mt][nt] = __builtin_amdgcn_mfma_f32_16x16x32_f16(am[mt], b_h, acc[mt][nt], 0, 0, 0);
        }
    }

    const float* bias = (wi == 0) ? bq : (wi == 1) ? bk : bv;
#pragma unroll
    for (int mt = 0; mt < 2; mt++)
#pragma unroll
        for (int nt = 0; nt < 4; nt++) {
            int n = nn0 + nt * 16 + lrow;
            float bias_v = bias[n];
            int hh = n >> 6, c = n & 63;
#pragma unroll
            for (int j = 0; j < 4; j++) {
                int m = m0 + mt * 16 + rbase + j;
                float v = acc[mt][nt][j] + bias_v;
                int b = m >> 11, s = m & 2047;
                if (wi == 0) {
                    size_t idx = ((size_t)(b * NH + hh) * SEQ + s) * HD + c;
                    qf[idx] = f32_to_f16(v);
                } else if (wi == 1) {
                    size_t idx = ((size_t)(b * NH + hh) * SEQ + s) * HD + c;
                    kf[idx] = f32_to_f16(v);
                } else {
                    size_t idx = ((size_t)(b * NH + hh) * HD + c) * SEQ + s;
                    vt[idx] = f32_to_f16(v);
                }
            }
        }
}

// ---------------- K2: fused attention ----------------
// One wg = one (b,h, 16-row Q tile). 8 waves, each owns 256 K-columns. fp16 single.
#define NW 8
__global__ __launch_bounds__(512, 4) void k_attn(
    const u16* __restrict__ qf, const u16* __restrict__ kf, const u16* __restrict__ vt,
    float* __restrict__ attn_out, u16* __restrict__ cf) {
    __shared__ float sm_m[NW][16];
    __shared__ float sm_l[NW][16];
    __shared__ u16 p_lds[NW][16][40];
    __shared__ float ctx_red[NW][16][68];

    int w = threadIdx.x >> 6, lane = threadIdx.x & 63;
    // XCD-chunked swizzle: 8192 wgs -> 1024/XCD = 8 heads/XCD (K/V L2 reuse)
    int bid0 = blockIdx.x;
    int bid = (bid0 & 7) * 1024 + (bid0 >> 3);
    int qt = bid & 127, bh = bid >> 7;
    int q0 = qt * 16;
    int lrow = lane & 15, lk8 = (lane >> 4) * 8, rbase = (lane >> 4) * 4;

    const u16* qp  = qf + (size_t)bh * SEQ * HD;
    const u16* kfp = kf + (size_t)bh * SEQ * HD;
    const u16* vtp = vt + (size_t)bh * HD * SEQ;

    // Q fragments fp16, 2 k-steps covering hd=64
    short8 aq[2];
#pragma unroll
    for (int kk = 0; kk < 2; kk++) {
        size_t o = (size_t)(q0 + lrow) * HD + kk * 32 + lk8;
        aq[kk] = *(const short8*)(qp + o);
    }

    f32x4 acc[16];
#pragma unroll
    for (int t = 0; t < 16; t++) acc[t] = (f32x4)0.f;

    int c0w = w * 256;
    int laneoff = lrow * HD + lk8;
#pragma unroll
    for (int t = 0; t < 16; t++) {
        int col0 = c0w + t * 16;
        const u16* kbase = kfp + (size_t)col0 * HD + laneoff;
#pragma unroll
        for (int kk = 0; kk < 2; kk++) {
            short8 bk_ = *(const short8*)(kbase + kk * 32);
            acc[t] = __builtin_amdgcn_mfma_f32_16x16x32_f16(aq[kk], bk_, acc[t], 0, 0, 0);
        }
    }

    // row max over this wave's 256 cols
    float mrow[4];
#pragma unroll
    for (int j = 0; j < 4; j++) {
        float m_ = acc[0][j];
#pragma unroll
        for (int t = 1; t < 16; t++) m_ = fmaxf(m_, acc[t][j]);
        for (int d = 1; d < 16; d <<= 1) m_ = fmaxf(m_, __shfl_xor(m_, d, 64));
        mrow[j] = m_;
    }
    if (lrow == 0) {
#pragma unroll
        for (int j = 0; j < 4; j++) sm_m[w][rbase + j] = mrow[j];
    }
    __syncthreads();
#pragma unroll
    for (int j = 0; j < 4; j++) {
        float M = sm_m[0][rbase + j];
#pragma unroll
        for (int w2 = 1; w2 < NW; w2++) M = fmaxf(M, sm_m[w2][rbase + j]);
        mrow[j] = M;
    }

    // exp + row sum; exp(0.125*(s-m)) == exp2(C*(s-m))
    const float C = 0.125f * 1.44269504088896f;
    float lsum[4];
#pragma unroll
    for (int j = 0; j < 4; j++) {
        float s_ = 0.f;
#pragma unroll
        for (int t = 0; t < 16; t++) {
            float e = exp2f((acc[t][j] - mrow[j]) * C);
            acc[t][j] = e;
            s_ += e;
        }
        for (int d = 1; d < 16; d <<= 1) s_ += __shfl_xor(s_, d, 64);
        lsum[j] = s_;
    }
    if (lrow == 0) {
#pragma unroll
        for (int j = 0; j < 4; j++) sm_l[w][rbase + j] = lsum[j];
    }
    __syncthreads();
    float inv[4];
#pragma unroll
    for (int j = 0; j < 4; j++) {
        float L = 0.f;
#pragma unroll
        for (int w2 = 0; w2 < NW; w2++) L += sm_l[w2][rbase + j];
        inv[j] = 1.f / L;
    }

    // normalize + write attn (fp32)
    float* attn_base = attn_out + ((size_t)bh * SEQ + q0) * SEQ;
#pragma unroll
    for (int t = 0; t < 16; t++) {
        int col = c0w + t * 16 + lrow;
#pragma unroll
        for (int j = 0; j < 4; j++) {
            float p = acc[t][j] * inv[j];
            acc[t][j] = p;
            attn_base[(size_t)(rbase + j) * SEQ + col] = p;
        }
    }

    // PV over this wave's 256 cols (P, V fp16)
    f32x4 cacc[4];
#pragma unroll
    for (int nt = 0; nt < 4; nt++) cacc[nt] = (f32x4)0.f;
#pragma unroll
    for (int c2 = 0; c2 < 8; c2++) {
#pragma unroll
        for (int tt = 0; tt < 2; tt++) {
            int t = c2 * 2 + tt;
#pragma unroll
            for (int j = 0; j < 4; j++)
                p_lds[w][rbase + j][tt * 16 + lrow] = f32_to_f16(acc[t][j]);
        }
        short8 pf = *(const short8*)&p_lds[w][lrow][lk8];
        int s0 = c0w + c2 * 32;
#pragma unroll
        for (int nt = 0; nt < 4; nt++) {
            short8 vf = *(const short8*)(vtp + (size_t)(nt * 16 + lrow) * SEQ + s0 + lk8);
            cacc[nt] = __builtin_amdgcn_mfma_f32_16x16x32_f16(pf, vf, cacc[nt], 0, 0, 0);
        }
    }

    // cross-wave ctx reduce + write ctx fp16 ([B,S,D])
#pragma unroll
    for (int nt = 0; nt < 4; nt++)
#pragma unroll
        for (int j = 0; j < 4; j++)
            ctx_red[w][rbase + j][nt * 16 + lrow] = cacc[nt][j];
    __syncthreads();
    int b = bh >> 4, h = bh & 15;
    int e0 = threadIdx.x * 2;
#pragma unroll
    for (int q = 0; q < 2; q++) {
        int e = e0 + q;
        int r = e >> 6, c = e & 63;
        float s = 0.f;
#pragma unroll
        for (int w2 = 0; w2 < NW; w2++) s += ctx_red[w2][r][c];
        size_t idx = ((size_t)b * SEQ + q0 + r) * DM + h * HD + c;
        cf[idx] = f32_to_f16(s);
    }
}

// ---------------- K3: output projection GEMM (single fp16 MFMA) ----------------
__global__ __launch_bounds__(256, 4) void k_gemm_out(
    const u16* __restrict__ af, const u16* __restrict__ wt,
    const float* __restrict__ bo, float* __restrict__ out) {
    int w = threadIdx.x >> 6, lane = threadIdx.x & 63;
    // XCD-chunked swizzle: 1024 wgs, 128/XCD
    int lin = blockIdx.y * 16 + blockIdx.x;
    int lin2 = (lin & 7) * 128 + (lin >> 3);
    int bx = lin2 % 16, by = lin2 / 16;
    int m0 = by * 128 + w * 32;
    int n0 = bx * 64;
    const u16* bhp = wt + ((size_t)3 << 20);
    int lrow = lane & 15, lk8 = (lane >> 4) * 8, rbase = (lane >> 4) * 4;

    f32x4 acc[2][4];
#pragma unroll
    for (int mt = 0; mt < 2; mt++)
#pragma unroll
        for (int nt = 0; nt < 4; nt++) acc[mt][nt] = (f32x4)0.f;

    for (int k = 0; k < 1024; k += 32) {
        short8 am[2];
#pragma unroll
        for (int mt = 0; mt < 2; mt++) {
            size_t ao = (size_t)(m0 + mt * 16 + lrow) * 1024 + k + lk8;
            am[mt] = *(const short8*)(af + ao);
        }
#pragma unroll
        for (int nt = 0; nt < 4; nt++) {
            size_t bo_ = (size_t)(n0 + nt * 16 + lrow) * 1024 + k + lk8;
            short8 b_h = *(const short8*)(bhp + bo_);
#pragma unroll
            for (int mt = 0; mt < 2; mt++)
                acc[mt][nt] = __builtin_amdgcn_mfma_f32_16x16x32_f16(am[mt], b_h, acc[mt][nt], 0, 0, 0);
        }
    }
#pragma unroll
    for (int mt = 0; mt < 2; mt++)
#pragma unroll
        for (int nt = 0; nt < 4; nt++) {
            int n = n0 + nt * 16 + lrow;
            float bias_v = bo[n];
#pragma unroll
            for (int j = 0; j < 4; j++) {
                int m = m0 + mt * 16 + rbase + j;
                out[(size_t)m * 1024 + n] = acc[mt][nt][j] + bias_v;
            }
        }
}

extern "C" void kernel_launch(void* const* d_in, const int* in_sizes, int n_in,
                              void* d_out, int out_size, void* d_ws, size_t ws_size,
                              hipStream_t stream) {
    const float* x  = (const float*)d_in[0];
    const float* wq = (const float*)d_in[1];
    const float* bq = (const float*)d_in[2];
    const float* wk = (const float*)d_in[3];
    const float* bk = (const float*)d_in[4];
    const float* wv = (const float*)d_in[5];
    const float* bv = (const float*)d_in[6];
    const float* wo = (const float*)d_in[7];
    const float* bo = (const float*)d_in[8];

    float* out  = (float*)d_out;
    float* attn = out + (size_t)BATCH * SEQ * DM;

    char* ws = (char*)d_ws;
    const size_t MB = 1u << 20;
    u16* x16  = (u16*)(ws + 0 * MB);    // 16 MiB
    u16* wt16 = (u16*)(ws + 16 * MB);   // 8 MiB (4 weights, [n][k], fp16)
    u16* qf   = (u16*)(ws + 24 * MB);   // 16 MiB
    u16* kf   = (u16*)(ws + 40 * MB);   // 16 MiB
    u16* vt   = (u16*)(ws + 56 * MB);   // 16 MiB
    u16* cf   = (u16*)(ws + 72 * MB);   // 16 MiB

    int n4 = BATCH * SEQ * DM / 4;
    k_split_x<<<(n4 + 255) / 256, 256, 0, stream>>>((const float4*)x, (ushort4*)x16, n4);
    k_split_w<<<4096, 256, 0, stream>>>(wq, wk, wv, wo, wt16);
    k_gemm_qkv<<<dim3(48, 64), 256, 0, stream>>>(x16, wt16, bq, bk, bv, qf, kf, vt);
    k_attn<<<BATCH * NH * (SEQ / 16), 512, 0, stream>>>(qf, kf, vt, attn, cf);
    k_gemm_out<<<dim3(16, 64), 256, 0, stream>>>(cf, wt16, bo, out);
}

// Round 5
// 737.831 us; speedup vs baseline: 2.9161x; 1.3174x over previous
//
#include <hip/hip_runtime.h>
#include <hip/hip_bf16.h>
#include <stdint.h>

typedef __attribute__((ext_vector_type(8))) short short8;
typedef __attribute__((ext_vector_type(4))) float f32x4;
typedef unsigned short u16;

#define BATCH 4
#define NH    16
#define SEQ   2048
#define DM    1024
#define HD    64

__device__ __forceinline__ u16 f32_to_f16(float f) {
    _Float16 h = (_Float16)f;
    return __builtin_bit_cast(unsigned short, h);
}
__device__ __forceinline__ float f16_to_f32(u16 u) {
    _Float16 h = __builtin_bit_cast(_Float16, u);
    return (float)h;
}

__device__ __forceinline__ void gload_lds16(const void* g, void* l) {
    __builtin_amdgcn_global_load_lds(
        (const __attribute__((address_space(1))) void*)g,
        (__attribute__((address_space(3))) void*)l, 16, 0, 0);
}

// ---------------- K0a: convert x to fp16 ----------------
__global__ void k_split_x(const float4* __restrict__ x, ushort4* __restrict__ xf, int n4) {
    int i = blockIdx.x * 256 + threadIdx.x;
    if (i >= n4) return;
    float4 v = x[i];
    float f[4] = {v.x, v.y, v.z, v.w};
    ushort4 h;
    u16* hp = (u16*)&h;
#pragma unroll
    for (int j = 0; j < 4; j++) hp[j] = f32_to_f16(f[j]);
    xf[i] = h;
}

// ---------------- K0b: transpose + convert the 4 weight matrices to fp16 ----------------
// out layout: wt[wi][n][k] (n-major), wi in {q,k,v,o}
__global__ void k_split_w(const float* __restrict__ w0, const float* __restrict__ w1,
                          const float* __restrict__ w2, const float* __restrict__ w3,
                          u16* __restrict__ wt) {
    __shared__ float tile[32][33];
    int bx = blockIdx.x;
    int wi = bx >> 10;
    int t  = bx & 1023;
    int kt = t >> 5, nt = t & 31;
    const float* w = (wi == 0) ? w0 : (wi == 1) ? w1 : (wi == 2) ? w2 : w3;
    int tx = threadIdx.x & 31, ty = threadIdx.x >> 5;
#pragma unroll
    for (int i = 0; i < 4; i++) {
        int r = ty + i * 8;
        tile[r][tx] = w[(size_t)(kt * 32 + r) * 1024 + nt * 32 + tx];
    }
    __syncthreads();
    size_t base = ((size_t)wi << 20);
#pragma unroll
    for (int i = 0; i < 4; i++) {
        int r = ty + i * 8;
        size_t dst = base + (size_t)(nt * 32 + r) * 1024 + kt * 32 + tx;
        wt[dst] = f32_to_f16(tile[tx][r]);
    }
}

// ================= m97-style 128x128 GEMM core =================
// A [M][1024] fp16 row-major, B [n][k] fp16 (n-major). BK=64, 4 waves, wave = 64x64.
// LDS tiles staged via global_load_lds w/ XOR slot swizzle (slot ^= row&7).
// Macro-free shared body via template on epilogue is overkill; duplicate the loop.

#define GEMM_KLOOP(Aptr, Bptr, am0, bn0)                                              \
    f32x4 acc[4][4];                                                                   \
    _Pragma("unroll")                                                                  \
    for (int mt = 0; mt < 4; mt++)                                                     \
        _Pragma("unroll")                                                              \
        for (int nt = 0; nt < 4; nt++) acc[mt][nt] = (f32x4)0.f;                       \
    int rowc = lane >> 3;                                                              \
    int slx  = (lane & 7) ^ rowc;   /* pre-swizzled source slot */                     \
    int kx   = slx << 3;                                                               \
    for (int k0 = 0; k0 < 1024; k0 += 64) {                                            \
        _Pragma("unroll")                                                              \
        for (int i = 0; i < 4; i++) {                                                  \
            int c = w * 4 + i;                                                         \
            int row = c * 8 + rowc;                                                    \
            gload_lds16(Aptr + (size_t)(am0 + row) * 1024 + k0 + kx,                   \
                        (char*)As + c * 1024 + lane * 16);                             \
            gload_lds16(Bptr + (size_t)(bn0 + row) * 1024 + k0 + kx,                   \
                        (char*)Bs + c * 1024 + lane * 16);                             \
        }                                                                              \
        __syncthreads();                                                               \
        _Pragma("unroll")                                                              \
        for (int kk = 0; kk < 2; kk++) {                                               \
            short8 af[4], bf[4];                                                       \
            _Pragma("unroll")                                                          \
            for (int mt = 0; mt < 4; mt++) {                                           \
                int row = wr * 64 + mt * 16 + lrow;                                    \
                int slot = (kk * 4 + (lane >> 4)) ^ (row & 7);                         \
                af[mt] = *(const short8*)(As + row * 64 + slot * 8);                   \
            }                                                                          \
            _Pragma("unroll")                                                          \
            for (int nt = 0; nt < 4; nt++) {                                           \
                int row = wc * 64 + nt * 16 + lrow;                                    \
                int slot = (kk * 4 + (lane >> 4)) ^ (row & 7);                         \
                bf[nt] = *(const short8*)(Bs + row * 64 + slot * 8);                   \
            }                                                                          \
            _Pragma("unroll")                                                          \
            for (int mt = 0; mt < 4; mt++)                                             \
                _Pragma("unroll")                                                      \
                for (int nt = 0; nt < 4; nt++)                                         \
                    acc[mt][nt] = __builtin_amdgcn_mfma_f32_16x16x32_f16(              \
                        af[mt], bf[nt], acc[mt][nt], 0, 0, 0);                         \
        }                                                                              \
        __syncthreads();                                                               \
    }

// ---------------- K1: QKV projection GEMM ----------------
__global__ __launch_bounds__(256) void k_gemm_qkv(
    const u16* __restrict__ xf, const u16* __restrict__ wt,
    const float* __restrict__ bq, const float* __restrict__ bk, const float* __restrict__ bv,
    u16* __restrict__ qf, u16* __restrict__ kf, u16* __restrict__ vt) {
    __shared__ u16 As[128 * 64];
    __shared__ u16 Bs[128 * 64];
    int lane = threadIdx.x & 63, w = threadIdx.x >> 6;
    int wr = w >> 1, wc = w & 1;
    int lrow = lane & 15, rbase = (lane >> 4) * 4;
    // XCD-chunked swizzle: 1536 wgs = 8 x 192
    int lin = blockIdx.y * 24 + blockIdx.x;
    int lin2 = (lin & 7) * 192 + (lin >> 3);
    int bx = lin2 % 24, by = lin2 / 24;
    int am0 = by * 128;
    int n0 = bx * 128;
    int wi = n0 >> 10;
    int nn0 = n0 & 1023;
    const u16* bmat = wt + ((size_t)wi << 20);

    GEMM_KLOOP(xf, bmat, am0, nn0)

    const float* bias = (wi == 0) ? bq : (wi == 1) ? bk : bv;
#pragma unroll
    for (int mt = 0; mt < 4; mt++)
#pragma unroll
        for (int nt = 0; nt < 4; nt++) {
            int n = nn0 + wc * 64 + nt * 16 + lrow;
            float bias_v = bias[n];
            int hh = n >> 6, c = n & 63;
#pragma unroll
            for (int j = 0; j < 4; j++) {
                int m = am0 + wr * 64 + mt * 16 + rbase + j;
                float v = acc[mt][nt][j] + bias_v;
                int b = m >> 11, s = m & 2047;
                if (wi == 0) {
                    size_t idx = ((size_t)(b * NH + hh) * SEQ + s) * HD + c;
                    qf[idx] = f32_to_f16(v);
                } else if (wi == 1) {
                    size_t idx = ((size_t)(b * NH + hh) * SEQ + s) * HD + c;
                    kf[idx] = f32_to_f16(v);
                } else {
                    size_t idx = ((size_t)(b * NH + hh) * HD + c) * SEQ + s;
                    vt[idx] = f32_to_f16(v);
                }
            }
        }
}

// ---------------- K3: output projection GEMM ----------------
__global__ __launch_bounds__(256) void k_gemm_out(
    const u16* __restrict__ af_in, const u16* __restrict__ wt,
    const float* __restrict__ bo, float* __restrict__ out) {
    __shared__ u16 As[128 * 64];
    __shared__ u16 Bs[128 * 64];
    int lane = threadIdx.x & 63, w = threadIdx.x >> 6;
    int wr = w >> 1, wc = w & 1;
    int lrow = lane & 15, rbase = (lane >> 4) * 4;
    // XCD-chunked swizzle: 512 wgs = 8 x 64
    int lin = blockIdx.y * 8 + blockIdx.x;
    int lin2 = (lin & 7) * 64 + (lin >> 3);
    int bx = lin2 % 8, by = lin2 / 8;
    int am0 = by * 128;
    int n0 = bx * 128;
    const u16* bmat = wt + ((size_t)3 << 20);

    GEMM_KLOOP(af_in, bmat, am0, n0)

#pragma unroll
    for (int mt = 0; mt < 4; mt++)
#pragma unroll
        for (int nt = 0; nt < 4; nt++) {
            int n = n0 + wc * 64 + nt * 16 + lrow;
            float bias_v = bo[n];
#pragma unroll
            for (int j = 0; j < 4; j++) {
                int m = am0 + wr * 64 + mt * 16 + rbase + j;
                out[(size_t)m * 1024 + n] = acc[mt][nt][j] + bias_v;
            }
        }
}

// ---------------- K2: fused attention (UNCHANGED from R4) ----------------
#define NW 8
__global__ __launch_bounds__(512, 4) void k_attn(
    const u16* __restrict__ qf, const u16* __restrict__ kf, const u16* __restrict__ vt,
    float* __restrict__ attn_out, u16* __restrict__ cf) {
    __shared__ float sm_m[NW][16];
    __shared__ float sm_l[NW][16];
    __shared__ u16 p_lds[NW][16][40];
    __shared__ float ctx_red[NW][16][68];

    int w = threadIdx.x >> 6, lane = threadIdx.x & 63;
    int bid0 = blockIdx.x;
    int bid = (bid0 & 7) * 1024 + (bid0 >> 3);
    int qt = bid & 127, bh = bid >> 7;
    int q0 = qt * 16;
    int lrow = lane & 15, lk8 = (lane >> 4) * 8, rbase = (lane >> 4) * 4;

    const u16* qp  = qf + (size_t)bh * SEQ * HD;
    const u16* kfp = kf + (size_t)bh * SEQ * HD;
    const u16* vtp = vt + (size_t)bh * HD * SEQ;

    short8 aq[2];
#pragma unroll
    for (int kk = 0; kk < 2; kk++) {
        size_t o = (size_t)(q0 + lrow) * HD + kk * 32 + lk8;
        aq[kk] = *(const short8*)(qp + o);
    }

    f32x4 acc[16];
#pragma unroll
    for (int t = 0; t < 16; t++) acc[t] = (f32x4)0.f;

    int c0w = w * 256;
    int laneoff = lrow * HD + lk8;
#pragma unroll
    for (int t = 0; t < 16; t++) {
        int col0 = c0w + t * 16;
        const u16* kbase = kfp + (size_t)col0 * HD + laneoff;
#pragma unroll
        for (int kk = 0; kk < 2; kk++) {
            short8 bk_ = *(const short8*)(kbase + kk * 32);
            acc[t] = __builtin_amdgcn_mfma_f32_16x16x32_f16(aq[kk], bk_, acc[t], 0, 0, 0);
        }
    }

    float mrow[4];
#pragma unroll
    for (int j = 0; j < 4; j++) {
        float m_ = acc[0][j];
#pragma unroll
        for (int t = 1; t < 16; t++) m_ = fmaxf(m_, acc[t][j]);
        for (int d = 1; d < 16; d <<= 1) m_ = fmaxf(m_, __shfl_xor(m_, d, 64));
        mrow[j] = m_;
    }
    if (lrow == 0) {
#pragma unroll
        for (int j = 0; j < 4; j++) sm_m[w][rbase + j] = mrow[j];
    }
    __syncthreads();
#pragma unroll
    for (int j = 0; j < 4; j++) {
        float M = sm_m[0][rbase + j];
#pragma unroll
        for (int w2 = 1; w2 < NW; w2++) M = fmaxf(M, sm_m[w2][rbase + j]);
        mrow[j] = M;
    }

    const float C = 0.125f * 1.44269504088896f;
    float lsum[4];
#pragma unroll
    for (int j = 0; j < 4; j++) {
        float s_ = 0.f;
#pragma unroll
        for (int t = 0; t < 16; t++) {
            float e = exp2f((acc[t][j] - mrow[j]) * C);
            acc[t][j] = e;
            s_ += e;
        }
        for (int d = 1; d < 16; d <<= 1) s_ += __shfl_xor(s_, d, 64);
        lsum[j] = s_;
    }
    if (lrow == 0) {
#pragma unroll
        for (int j = 0; j < 4; j++) sm_l[w][rbase + j] = lsum[j];
    }
    __syncthreads();
    float inv[4];
#pragma unroll
    for (int j = 0; j < 4; j++) {
        float L = 0.f;
#pragma unroll
        for (int w2 = 0; w2 < NW; w2++) L += sm_l[w2][rbase + j];
        inv[j] = 1.f / L;
    }

    float* attn_base = attn_out + ((size_t)bh * SEQ + q0) * SEQ;
#pragma unroll
    for (int t = 0; t < 16; t++) {
        int col = c0w + t * 16 + lrow;
#pragma unroll
        for (int j = 0; j < 4; j++) {
            float p = acc[t][j] * inv[j];
            acc[t][j] = p;
            attn_base[(size_t)(rbase + j) * SEQ + col] = p;
        }
    }

    f32x4 cacc[4];
#pragma unroll
    for (int nt = 0; nt < 4; nt++) cacc[nt] = (f32x4)0.f;
#pragma unroll
    for (int c2 = 0; c2 < 8; c2++) {
#pragma unroll
        for (int tt = 0; tt < 2; tt++) {
            int t = c2 * 2 + tt;
#pragma unroll
            for (int j = 0; j < 4; j++)
                p_lds[w][rbase + j][tt * 16 + lrow] = f32_to_f16(acc[t][j]);
        }
        short8 pf = *(const short8*)&p_lds[w][lrow][lk8];
        int s0 = c0w + c2 * 32;
#pragma unroll
        for (int nt = 0; nt < 4; nt++) {
            short8 vf = *(const short8*)(vtp + (size_t)(nt * 16 + lrow) * SEQ + s0 + lk8);
            cacc[nt] = __builtin_amdgcn_mfma_f32_16x16x32_f16(pf, vf, cacc[nt], 0, 0, 0);
        }
    }

#pragma unroll
    for (int nt = 0; nt < 4; nt++)
#pragma unroll
        for (int j = 0; j < 4; j++)
            ctx_red[w][rbase + j][nt * 16 + lrow] = cacc[nt][j];
    __syncthreads();
    int b = bh >> 4, h = bh & 15;
    int e0 = threadIdx.x * 2;
#pragma unroll
    for (int q = 0; q < 2; q++) {
        int e = e0 + q;
        int r = e >> 6, c = e & 63;
        float s = 0.f;
#pragma unroll
        for (int w2 = 0; w2 < NW; w2++) s += ctx_red[w2][r][c];
        size_t idx = ((size_t)b * SEQ + q0 + r) * DM + h * HD + c;
        cf[idx] = f32_to_f16(s);
    }
}

extern "C" void kernel_launch(void* const* d_in, const int* in_sizes, int n_in,
                              void* d_out, int out_size, void* d_ws, size_t ws_size,
                              hipStream_t stream) {
    const float* x  = (const float*)d_in[0];
    const float* wq = (const float*)d_in[1];
    const float* bq = (const float*)d_in[2];
    const float* wk = (const float*)d_in[3];
    const float* bk = (const float*)d_in[4];
    const float* wv = (const float*)d_in[5];
    const float* bv = (const float*)d_in[6];
    const float* wo = (const float*)d_in[7];
    const float* bo = (const float*)d_in[8];

    float* out  = (float*)d_out;
    float* attn = out + (size_t)BATCH * SEQ * DM;

    char* ws = (char*)d_ws;
    const size_t MB = 1u << 20;
    u16* x16  = (u16*)(ws + 0 * MB);    // 16 MiB
    u16* wt16 = (u16*)(ws + 16 * MB);   // 8 MiB (4 weights, [n][k], fp16)
    u16* qf   = (u16*)(ws + 24 * MB);   // 16 MiB
    u16* kf   = (u16*)(ws + 40 * MB);   // 16 MiB
    u16* vt   = (u16*)(ws + 56 * MB);   // 16 MiB
    u16* cf   = (u16*)(ws + 72 * MB);   // 16 MiB

    int n4 = BATCH * SEQ * DM / 4;
    k_split_x<<<(n4 + 255) / 256, 256, 0, stream>>>((const float4*)x, (ushort4*)x16, n4);
    k_split_w<<<4096, 256, 0, stream>>>(wq, wk, wv, wo, wt16);
    k_gemm_qkv<<<dim3(24, 64), 256, 0, stream>>>(x16, wt16, bq, bk, bv, qf, kf, vt);
    k_attn<<<BATCH * NH * (SEQ / 16), 512, 0, stream>>>(qf, kf, vt, attn, cf);
    k_gemm_out<<<dim3(8, 64), 256, 0, stream>>>(cf, wt16, bo, out);
}